// Round 5
// baseline (87.692 us; speedup 1.0000x reference)
//
#include <hip/hip_runtime.h>
#include <math.h>

// Problem constants (match reference)
constexpr int NB     = 8192;        // batch rows
constexpr int TO     = 720;         // forecast/target length
constexpr int TI     = 1440;        // insample length
constexpr int FRQ    = 24;          // seasonal lag
constexpr int NV4    = TO / 4;      // 180 float4 per row
constexpr int NDIFF  = TI - FRQ;    // 1416 diffs per row
constexpr int NDIFF4 = NDIFF / 4;   // 354 float4 diffs per row
constexpr int WPB    = 4;           // waves per block
constexpr int NBLK   = NB / WPB;    // 2048 blocks

__device__ __forceinline__ float wredMax(float v) {
#pragma unroll
    for (int o = 32; o > 0; o >>= 1) v = fmaxf(v, __shfl_xor(v, o, 64));
    return v;
}
__device__ __forceinline__ float wredSum(float v) {
#pragma unroll
    for (int o = 32; o > 0; o >>= 1) v += __shfl_xor(v, o, 64);
    return v;
}

// Single fused kernel. One WAVE per row (barrier-free butterflies, all 21
// global loads prefetched up front), then a deterministic last-block
// finalize: blocks bump a monotonic counter in ws; the block whose
// (old+1) % NBLK == 0 reduces all 8192 partials in fixed order. The modulo
// test selects exactly one winner per call for ANY initial counter value,
// so the harness's 0xAA poison of ws needs no reset and the summation
// order (hence the output bits) is identical every call.
__global__ __launch_bounds__(256, 4) void tildeq_fused_kernel(
    const float* __restrict__ insample,
    const float* __restrict__ forecast,
    const float* __restrict__ target,
    const float* __restrict__ mask,
    float* __restrict__ ws,          // [0..NB): row partials; [NB]: counter
    float* __restrict__ out)
{
    const int lane = threadIdx.x & 63;
    const int b = blockIdx.x * WPB + (threadIdx.x >> 6);   // row = global wave id

    const float4* __restrict__ f4 = (const float4*)(forecast + (size_t)b * TO);
    const float4* __restrict__ g4 = (const float4*)(target   + (size_t)b * TO);
    const float4* __restrict__ m4 = (const float4*)(mask     + (size_t)b * TO);
    const float4* __restrict__ i4 = (const float4*)(insample + (size_t)b * TI);

    // Slot 2 of the 180-float4 row covers lanes 0..51 only; tail lanes clamp
    // the index (broadcast load, no branch) and gate their contributions.
    const bool act2 = (lane + 128) < NV4;
    const int  x2   = act2 ? (lane + 128) : (NV4 - 1);
    // insample diff tail: idx5 = lane+320 valid only for lanes < 34.
    const bool act5 = (lane + 320) < NDIFF4;
    const int  x5   = act5 ? (lane + 320) : (NDIFF4 - 1);

    // ---------------- issue ALL loads before any consumption ----------------
    const float4 fa0 = f4[lane      ], ga0 = g4[lane      ], ma0 = m4[lane      ];
    const float4 fa1 = f4[lane +  64], ga1 = g4[lane +  64], ma1 = m4[lane +  64];
    const float4 fa2 = f4[x2        ], ga2 = g4[x2        ], ma2 = m4[x2        ];
    const float4 ia0 = i4[lane      ], ic0 = i4[lane +   6];
    const float4 ia1 = i4[lane +  64], ic1 = i4[lane +  70];
    const float4 ia2 = i4[lane + 128], ic2 = i4[lane + 134];
    const float4 ia3 = i4[lane + 192], ic3 = i4[lane + 198];
    const float4 ia4 = i4[lane + 256], ic4 = i4[lane + 262];
    const float4 ia5 = i4[x5        ], ic5 = i4[x5   +   6];

    // ---------------- consume in issue order ----------------
    float dyy[3][4];
    float lmax = -INFINITY, smape_p = 0.f, mase_p = 0.f;

    auto proc = [&](const float4& fa, const float4& ga, const float4& ma,
                    float* dy) {
        const float fv[4] = {fa.x, fa.y, fa.z, fa.w};
        const float gv[4] = {ga.x, ga.y, ga.z, ga.w};
        const float mv[4] = {ma.x, ma.y, ma.z, ma.w};
#pragma unroll
        for (int j = 0; j < 4; ++j) {
            float d  = gv[j] - fv[j];
            float ad = fabsf(d);
            dy[j] = d * mv[j];                        // (target-forecast)*mask
            lmax = fmaxf(lmax, dy[j]);
            mase_p += ad * mv[j];                     // |t-f|*mask
            float den = fabsf(fv[j]) + fabsf(gv[j]);  // detached denom
            float r = (den > 0.f) ? ad * __builtin_amdgcn_rcpf(den) : 0.f;
            if (!(r < INFINITY)) r = 0.f;             // kill +inf/NaN
            smape_p += r * mv[j];
        }
    };

    proc(fa0, ga0, ma0, dyy[0]);
    proc(fa1, ga1, ma1, dyy[1]);
    if (act2) {
        proc(fa2, ga2, ma2, dyy[2]);
    } else {
#pragma unroll
        for (int j = 0; j < 4; ++j) dyy[2][j] = -INFINITY;  // exp -> 0
    }

    auto d4 = [](const float4& a, const float4& c) {
        return fabsf(c.x - a.x) + fabsf(c.y - a.y)
             + fabsf(c.z - a.z) + fabsf(c.w - a.w);
    };
    float masep_p = d4(ia0, ic0) + d4(ia1, ic1) + d4(ia2, ic2)
                  + d4(ia3, ic3) + d4(ia4, ic4);
    if (act5) masep_p += d4(ia5, ic5);

    // Stage 1: row max (6 shuffles).
    const float rmax = wredMax(lmax);

    // exp over register-resident dyy (inactive slots: exp(-inf)=0).
    float pexp[3][4];
    float sume_p = 0.f;
#pragma unroll
    for (int k = 0; k < 3; ++k)
#pragma unroll
        for (int j = 0; j < 4; ++j) {
            pexp[k][j] = __expf(dyy[k][j] - rmax);
            sume_p += pexp[k][j];
        }

    // Stage 2: fused 4-wide butterfly for the independent sums.
    float s0 = sume_p, s1 = smape_p, s2 = mase_p, s3 = masep_p;
#pragma unroll
    for (int o = 32; o > 0; o >>= 1) {
        s0 += __shfl_xor(s0, o, 64);
        s1 += __shfl_xor(s1, o, 64);
        s2 += __shfl_xor(s2, o, 64);
        s3 += __shfl_xor(s3, o, 64);
    }
    const float sume = s0, smape = s1, mase = s2, msum = s3;

    // Stage 3: eq-sum (needs sume). Only ACTIVE slots contribute |1/T - p|.
    const float inv_sume = 1.0f / sume;
    float eq_p = 0.f;
#pragma unroll
    for (int k = 0; k < 2; ++k)
#pragma unroll
        for (int j = 0; j < 4; ++j)
            eq_p += fabsf(1.0f / (float)TO - pexp[k][j] * inv_sume);
    if (act2) {
#pragma unroll
        for (int j = 0; j < 4; ++j)
            eq_p += fabsf(1.0f / (float)TO - pexp[2][j] * inv_sume);
    }
    const float eqsum = wredSum(eq_p);

    if (lane == 0) {
        float masep = msum / (float)NDIFF;
        float invm  = (masep == 0.f) ? 0.f : (1.0f / masep);  // divide_no_nan
        if (!(invm < INFINITY)) invm = 0.f;
        float contrib =
            (0.99f * (float)TO / (4.0f * (float)NB)) * eqsum   // mean(loss_TILDEQ)/4
          + (200.0f / ((float)NB * (float)TO)) * smape         // 200*smape
          + (1.0f  / ((float)NB * (float)TO)) * mase * invm;   // MASE term
        ws[b] = contrib;
    }

    // ---------------- deterministic last-block finalize ----------------
    __shared__ int isLast;
    __syncthreads();                         // all 4 rows of this block written
    if (threadIdx.x == 0) {
        __threadfence();                     // release: ws[b] visible device-wide
        unsigned old = atomicAdd((unsigned*)(ws + NB), 1u);
        isLast = (((old + 1u) & (unsigned)(NBLK - 1)) == 0u);
    }
    __syncthreads();
    if (!isLast) return;

    __threadfence();                         // acquire: see all blocks' ws stores
    const float4* w4 = (const float4*)ws;
    float s = 0.f;
#pragma unroll
    for (int i = threadIdx.x; i < NB / 4; i += 256) {
        float4 v = w4[i];
        s += (v.x + v.y) + (v.z + v.w);
    }
    s = wredSum(s);
    __shared__ float lds[4];
    if ((threadIdx.x & 63) == 0) lds[threadIdx.x >> 6] = s;
    __syncthreads();
    if (threadIdx.x == 0)
        out[0] = (lds[0] + lds[1]) + (lds[2] + lds[3]);
}

extern "C" void kernel_launch(void* const* d_in, const int* in_sizes, int n_in,
                              void* d_out, int out_size, void* d_ws, size_t ws_size,
                              hipStream_t stream)
{
    // setup_inputs order: insample, freq, forecast, target, mask
    const float* insample = (const float*)d_in[0];
    const float* forecast = (const float*)d_in[2];
    const float* target   = (const float*)d_in[3];
    const float* mask     = (const float*)d_in[4];
    float* ws  = (float*)d_ws;   // [0..NB) partials, [NB] monotonic counter
    float* out = (float*)d_out;

    tildeq_fused_kernel<<<NBLK, 256, 0, stream>>>(insample, forecast, target,
                                                  mask, ws, out);
}

// Round 7
// 26.896 us; speedup vs baseline: 3.2604x; 3.2604x over previous
//
#include <hip/hip_runtime.h>
#include <math.h>

// Problem constants (match reference)
constexpr int NB     = 8192;        // batch rows
constexpr int TO     = 720;         // forecast/target length
constexpr int TI     = 1440;        // insample length
constexpr int FRQ    = 24;          // seasonal lag
constexpr int NV4    = TO / 4;      // 180 float4 per row
constexpr int NDIFF  = TI - FRQ;    // 1416 diffs per row
constexpr int NDIFF4 = NDIFF / 4;   // 354 float4 diffs per row
constexpr int NROW4  = TI / 4;      // 360 float4 per insample row
constexpr int WPB    = 4;           // waves per block
constexpr int NBLK   = NB / WPB;    // 2048 blocks

__device__ __forceinline__ float wredMax(float v) {
#pragma unroll
    for (int o = 32; o > 0; o >>= 1) v = fmaxf(v, __shfl_xor(v, o, 64));
    return v;
}
__device__ __forceinline__ float wredSum(float v) {
#pragma unroll
    for (int o = 32; o > 0; o >>= 1) v += __shfl_xor(v, o, 64);
    return v;
}

// One WAVE per row, barrier-free, all global loads prefetched up front.
// insample is loaded ONCE (6 disjoint lane-contiguous float4 slices); the
// +24-element (= +6 float4) shifted operand of the seasonal diff is derived
// with cross-lane shuffles (shfl_down(cur,6) for lanes<58, shfl_up(next,58)
// for the 6 boundary lanes) instead of a second, 91%-overlapping load.
// This cuts per-wave streamed bytes 21.5KB -> 15.5KB; with L1 thrashing at
// 32 streaming waves/CU the old second touch went to L2/L3, so total
// L2/L3-side traffic drops ~165MB -> 118MB (the mandatory minimum).
__global__ __launch_bounds__(256, 4) void tildeq_row_kernel(
    const float* __restrict__ insample,
    const float* __restrict__ forecast,
    const float* __restrict__ target,
    const float* __restrict__ mask,
    float* __restrict__ ws)
{
    const int lane = threadIdx.x & 63;
    const int b = blockIdx.x * WPB + (threadIdx.x >> 6);   // row = global wave id

    const float4* __restrict__ f4 = (const float4*)(forecast + (size_t)b * TO);
    const float4* __restrict__ g4 = (const float4*)(target   + (size_t)b * TO);
    const float4* __restrict__ m4 = (const float4*)(mask     + (size_t)b * TO);
    const float4* __restrict__ i4 = (const float4*)(insample + (size_t)b * TI);

    // Slot 2 of the 180-float4 f/t/m row covers lanes 0..51 only; tail lanes
    // clamp the index (broadcast load) and gate their contributions.
    const bool act2 = (lane + 128) < NV4;
    const int  x2   = act2 ? (lane + 128) : (NV4 - 1);
    // insample slice 5: diffs need i in [320,354) (lanes<34); its shifted
    // operand reaches a[359]. Clamp loads to the row end (idx<=359).
    const bool act5 = (lane + 320) < NDIFF4;
    const int  x5   = (lane + 320 < NROW4) ? (lane + 320) : (NROW4 - 1);

    // ---------------- issue ALL loads before any consumption ----------------
    const float4 fa0 = f4[lane      ], ga0 = g4[lane      ], ma0 = m4[lane      ];
    const float4 fa1 = f4[lane +  64], ga1 = g4[lane +  64], ma1 = m4[lane +  64];
    const float4 fa2 = f4[x2        ], ga2 = g4[x2        ], ma2 = m4[x2        ];
    const float4 s0v = i4[lane      ];
    const float4 s1v = i4[lane +  64];
    const float4 s2v = i4[lane + 128];
    const float4 s3v = i4[lane + 192];
    const float4 s4v = i4[lane + 256];
    const float4 s5v = i4[x5        ];

    // ---------------- consume in issue order ----------------
    float dyy[3][4];
    float lmax = -INFINITY, smape_p = 0.f, mase_p = 0.f;

    auto proc = [&](const float4& fa, const float4& ga, const float4& ma,
                    float* dy) {
        const float fv[4] = {fa.x, fa.y, fa.z, fa.w};
        const float gv[4] = {ga.x, ga.y, ga.z, ga.w};
        const float mv[4] = {ma.x, ma.y, ma.z, ma.w};
#pragma unroll
        for (int j = 0; j < 4; ++j) {
            float d  = gv[j] - fv[j];
            float ad = fabsf(d);
            dy[j] = d * mv[j];                        // (target-forecast)*mask
            lmax = fmaxf(lmax, dy[j]);
            mase_p += ad * mv[j];                     // |t-f|*mask
            float den = fabsf(fv[j]) + fabsf(gv[j]);  // detached denom
            float r = (den > 0.f) ? ad * __builtin_amdgcn_rcpf(den) : 0.f;
            if (!(r < INFINITY)) r = 0.f;             // kill +inf/NaN
            smape_p += r * mv[j];
        }
    };

    proc(fa0, ga0, ma0, dyy[0]);
    proc(fa1, ga1, ma1, dyy[1]);
    if (act2) {
        proc(fa2, ga2, ma2, dyy[2]);
    } else {
#pragma unroll
        for (int j = 0; j < 4; ++j) dyy[2][j] = -INFINITY;  // exp -> 0
    }

    // Shifted slice: element-wise a[i+6] from (cur, next) via shuffles.
    const bool lo58 = lane < 58;
    auto shift6 = [&](const float4& cur, const float4& nxt) -> float4 {
        float4 r;
        float dx = __shfl_down(cur.x, 6, 64), ux = __shfl_up(nxt.x, 58, 64);
        float dy_ = __shfl_down(cur.y, 6, 64), uy = __shfl_up(nxt.y, 58, 64);
        float dz = __shfl_down(cur.z, 6, 64), uz = __shfl_up(nxt.z, 58, 64);
        float dw = __shfl_down(cur.w, 6, 64), uw = __shfl_up(nxt.w, 58, 64);
        r.x = lo58 ? dx : ux;  r.y = lo58 ? dy_ : uy;
        r.z = lo58 ? dz : uz;  r.w = lo58 ? dw : uw;
        return r;
    };
    auto d4 = [](const float4& a, const float4& c) {
        return fabsf(c.x - a.x) + fabsf(c.y - a.y)
             + fabsf(c.z - a.z) + fabsf(c.w - a.w);
    };
    float masep_p = d4(s0v, shift6(s0v, s1v))
                  + d4(s1v, shift6(s1v, s2v))
                  + d4(s2v, shift6(s2v, s3v))
                  + d4(s3v, shift6(s3v, s4v))
                  + d4(s4v, shift6(s4v, s5v));
    {   // slice 5: only lanes 0..33 are real diffs (i<354); they need only
        // shfl_down (l+6 <= 39 < 58), but all lanes run the shuffle.
        float4 c5 = shift6(s5v, s5v);
        if (act5) masep_p += d4(s5v, c5);
    }

    // Stage 1: row max (6 shuffles).
    const float rmax = wredMax(lmax);

    // exp over register-resident dyy (inactive slots: exp(-inf)=0).
    float pexp[3][4];
    float sume_p = 0.f;
#pragma unroll
    for (int k = 0; k < 3; ++k)
#pragma unroll
        for (int j = 0; j < 4; ++j) {
            pexp[k][j] = __expf(dyy[k][j] - rmax);
            sume_p += pexp[k][j];
        }

    // Stage 2: fused 4-wide butterfly for the independent sums.
    float s0 = sume_p, s1 = smape_p, s2 = mase_p, s3 = masep_p;
#pragma unroll
    for (int o = 32; o > 0; o >>= 1) {
        s0 += __shfl_xor(s0, o, 64);
        s1 += __shfl_xor(s1, o, 64);
        s2 += __shfl_xor(s2, o, 64);
        s3 += __shfl_xor(s3, o, 64);
    }
    const float sume = s0, smape = s1, mase = s2, msum = s3;

    // Stage 3: eq-sum (needs sume). Only ACTIVE slots contribute |1/T - p|.
    const float inv_sume = 1.0f / sume;
    float eq_p = 0.f;
#pragma unroll
    for (int k = 0; k < 2; ++k)
#pragma unroll
        for (int j = 0; j < 4; ++j)
            eq_p += fabsf(1.0f / (float)TO - pexp[k][j] * inv_sume);
    if (act2) {
#pragma unroll
        for (int j = 0; j < 4; ++j)
            eq_p += fabsf(1.0f / (float)TO - pexp[2][j] * inv_sume);
    }
    const float eqsum = wredSum(eq_p);

    if (lane == 0) {
        float masep = msum / (float)NDIFF;
        float invm  = (masep == 0.f) ? 0.f : (1.0f / masep);  // divide_no_nan
        if (!(invm < INFINITY)) invm = 0.f;
        float contrib =
            (0.99f * (float)TO / (4.0f * (float)NB)) * eqsum   // mean(loss_TILDEQ)/4
          + (200.0f / ((float)NB * (float)TO)) * smape         // 200*smape
          + (1.0f  / ((float)NB * (float)TO)) * mase * invm;   // MASE term
        ws[b] = contrib;
    }
}

// Deterministic final reduction of the 8192 per-row contributions.
__global__ __launch_bounds__(256) void tildeq_finalize_kernel(
    const float* __restrict__ ws, float* __restrict__ out)
{
    __shared__ float lds[4];
    const int lane = threadIdx.x & 63, w = threadIdx.x >> 6;
    const float4* w4 = (const float4*)ws;
    float s = 0.f;
#pragma unroll
    for (int i = threadIdx.x; i < NB / 4; i += 256) {
        float4 v = w4[i];
        s += (v.x + v.y) + (v.z + v.w);
    }
    s = wredSum(s);
    if (lane == 0) lds[w] = s;
    __syncthreads();
    if (threadIdx.x == 0)
        out[0] = (lds[0] + lds[1]) + (lds[2] + lds[3]);
}

extern "C" void kernel_launch(void* const* d_in, const int* in_sizes, int n_in,
                              void* d_out, int out_size, void* d_ws, size_t ws_size,
                              hipStream_t stream)
{
    // setup_inputs order: insample, freq, forecast, target, mask
    const float* insample = (const float*)d_in[0];
    const float* forecast = (const float*)d_in[2];
    const float* target   = (const float*)d_in[3];
    const float* mask     = (const float*)d_in[4];
    float* ws  = (float*)d_ws;   // 8192 floats of per-row partials
    float* out = (float*)d_out;

    tildeq_row_kernel<<<NBLK, 256, 0, stream>>>(insample, forecast, target, mask, ws);
    tildeq_finalize_kernel<<<1, 256, 0, stream>>>(ws, out);
}